// Round 4
// baseline (934.930 us; speedup 1.0000x reference)
//
#include <hip/hip_runtime.h>
#include <hip/hip_bf16.h>
#include <cstdint>
#include <cstddef>

// Problem dims
#define BDIM 8192
#define D1 1024
#define HDIM 4096

// GEMM tile
#define BM 128
#define BN 128
#define BK 64

typedef __attribute__((ext_vector_type(8))) short short8;
typedef __attribute__((ext_vector_type(4))) float f32x4;

__device__ inline void async_load16(const void* g, void* l) {
  __builtin_amdgcn_global_load_lds(
      (const __attribute__((address_space(1))) void*)g,
      (__attribute__((address_space(3))) void*)l,
      16 /*bytes*/, 0 /*offset*/, 0 /*aux*/);
}

__device__ inline unsigned short f2bf(float f) {
  union { float f; uint32_t u; } v; v.f = f;
  uint32_t u = v.u;
  uint32_t r = u + 0x7FFFu + ((u >> 16) & 1u);  // RNE
  return (unsigned short)(r >> 16);
}

// ---------------------------------------------------------------------------
// Single-acc GEMM core (R2-proven, ~808 TF): C[M,N] = A[M,K] @ B[N,K]^T.
// mode 0: +bias, ReLU, bf16 out (ldc=N, roff=coff=0).
// mode 1: +bias, fp32 out at C[(roff+row)*ldc + coff + col].
// grid: (N/BN, M/BM, z); z picks {s,t} pointer set (use z=1 for single).
// ---------------------------------------------------------------------------
__global__ __launch_bounds__(256, 2)
void gemm_bt(const unsigned short* __restrict__ A0,
             const unsigned short* __restrict__ A1,
             const unsigned short* __restrict__ B0,
             const unsigned short* __restrict__ B1,
             const float* __restrict__ bias0,
             const float* __restrict__ bias1,
             void* __restrict__ C0v, void* __restrict__ C1v,
             int M, int N, int K, int mode, int ldc, int coff, int roff) {
  const unsigned short* A = blockIdx.z ? A1 : A0;
  const unsigned short* B = blockIdx.z ? B1 : B0;
  const float* bias = blockIdx.z ? bias1 : bias0;

  __shared__ __align__(16) unsigned short lsA[BM * BK];
  __shared__ __align__(16) unsigned short lsB[BN * BK];

  const int tid  = threadIdx.x;
  const int wave = tid >> 6;
  const int lane = tid & 63;
  const int quad = lane >> 4;
  const int l15  = lane & 15;

  const int m0 = blockIdx.y * BM;
  const int n0 = blockIdx.x * BN;
  const int wrow = (wave >> 1) * 64;   // wave tile 64x64, 2x2 wave grid
  const int wcol = (wave & 1) * 64;

  f32x4 acc[4][4] = {};

  for (int k0 = 0; k0 < K; k0 += BK) {
    __syncthreads();
    // XOR swizzle: phys granule s holds logical (row = s>>3, kg = (s&7)^(row&7)).
#pragma unroll
    for (int i = 0; i < 4; ++i) {
      int s   = (wave * 4 + i) * 64 + lane;
      int row = s >> 3;
      int kg  = (s & 7) ^ (row & 7);
      async_load16(A + (long)(m0 + row) * K + k0 + kg * 8, &lsA[(wave * 4 + i) * 512]);
      async_load16(B + (long)(n0 + row) * K + k0 + kg * 8, &lsB[(wave * 4 + i) * 512]);
    }
    __syncthreads();

#pragma unroll
    for (int ks = 0; ks < 2; ++ks) {
      short8 af[4], bfr[4];
      const int kg = ks * 4 + quad;
#pragma unroll
      for (int t = 0; t < 4; ++t) {
        int row = wrow + t * 16 + l15;
        af[t] = *(const short8*)&lsA[(row * 8 + (kg ^ (row & 7))) * 8];
        int col = wcol + t * 16 + l15;
        bfr[t] = *(const short8*)&lsB[(col * 8 + (kg ^ (col & 7))) * 8];
      }
#pragma unroll
      for (int mt = 0; mt < 4; ++mt)
#pragma unroll
        for (int nt = 0; nt < 4; ++nt)
          acc[mt][nt] = __builtin_amdgcn_mfma_f32_16x16x32_bf16(
              af[mt], bfr[nt], acc[mt][nt], 0, 0, 0);
    }
  }

  // Epilogue. C/D layout: col = lane&15, row = quad*4 + reg  [m89/m91 verified]
  if (mode == 0) {
    unsigned short* C = blockIdx.z ? (unsigned short*)C1v : (unsigned short*)C0v;
#pragma unroll
    for (int nt = 0; nt < 4; ++nt) {
      int col = n0 + wcol + nt * 16 + l15;
      float bv = bias[col];
#pragma unroll
      for (int mt = 0; mt < 4; ++mt)
#pragma unroll
        for (int r = 0; r < 4; ++r) {
          long row = m0 + wrow + mt * 16 + quad * 4 + r;
          float v = acc[mt][nt][r] + bv;
          C[row * ldc + col] = f2bf(v > 0.f ? v : 0.f);
        }
    }
  } else {
    float* C = blockIdx.z ? (float*)C1v : (float*)C0v;
#pragma unroll
    for (int nt = 0; nt < 4; ++nt) {
      int col = n0 + wcol + nt * 16 + l15;
      float bv = bias[col];
#pragma unroll
      for (int mt = 0; mt < 4; ++mt)
#pragma unroll
        for (int r = 0; r < 4; ++r) {
          long row = roff + m0 + wrow + mt * 16 + quad * 4 + r;
          C[row * ldc + coff + col] = acc[mt][nt][r] + bv;
        }
    }
  }
}

// ---------------------------------------------------------------------------
// Layer-2 s-path GEMM + fused coupling epilogue (single acc).
// s = A@B^T + bias (K=4096, N=1024). Then sv=tanh(s);
// y = x[:,off+col]*exp(sv) + y_out[:,off+col] (t was written there by the
// preceding t-dispatch); y overwrites y_out; optionally y bf16 -> y_bf;
// rowsum(sv) -> atomicAdd ld_out.
// grid: (1024/BN, Mrows/BM).
// ---------------------------------------------------------------------------
__global__ __launch_bounds__(256, 2)
void gemm2_s(const unsigned short* __restrict__ A,
             const unsigned short* __restrict__ B,
             const float* __restrict__ bias,
             const float* __restrict__ x,
             float* __restrict__ y_out,
             unsigned short* __restrict__ y_bf,
             float* __restrict__ ld_out,
             int moff, int off) {
  const int K = 4096;
  __shared__ __align__(16) unsigned short lsA[BM * BK];
  __shared__ __align__(16) unsigned short lsB[BN * BK];
  __shared__ float rowsum[BM];

  const int tid  = threadIdx.x;
  const int wave = tid >> 6;
  const int lane = tid & 63;
  const int quad = lane >> 4;
  const int l15  = lane & 15;

  const int m0 = blockIdx.y * BM;
  const int n0 = blockIdx.x * BN;
  const int wrow = (wave >> 1) * 64;
  const int wcol = (wave & 1) * 64;

  f32x4 acc[4][4] = {};

  for (int k0 = 0; k0 < K; k0 += BK) {
    __syncthreads();
#pragma unroll
    for (int i = 0; i < 4; ++i) {
      int s   = (wave * 4 + i) * 64 + lane;
      int row = s >> 3;
      int kg  = (s & 7) ^ (row & 7);
      async_load16(A + (long)(m0 + row) * K + k0 + kg * 8, &lsA[(wave * 4 + i) * 512]);
      async_load16(B + (long)(n0 + row) * K + k0 + kg * 8, &lsB[(wave * 4 + i) * 512]);
    }
    __syncthreads();

#pragma unroll
    for (int ks = 0; ks < 2; ++ks) {
      short8 af[4], bfr[4];
      const int kg = ks * 4 + quad;
#pragma unroll
      for (int t = 0; t < 4; ++t) {
        int row = wrow + t * 16 + l15;
        af[t] = *(const short8*)&lsA[(row * 8 + (kg ^ (row & 7))) * 8];
        int col = wcol + t * 16 + l15;
        bfr[t] = *(const short8*)&lsB[(col * 8 + (kg ^ (col & 7))) * 8];
      }
#pragma unroll
      for (int mt = 0; mt < 4; ++mt)
#pragma unroll
        for (int nt = 0; nt < 4; ++nt)
          acc[mt][nt] = __builtin_amdgcn_mfma_f32_16x16x32_bf16(
              af[mt], bfr[nt], acc[mt][nt], 0, 0, 0);
    }
  }

  // --- fused coupling epilogue ---
  if (tid < BM) rowsum[tid] = 0.f;
  __syncthreads();

  float bvs[4];
#pragma unroll
  for (int nt = 0; nt < 4; ++nt) bvs[nt] = bias[n0 + wcol + nt * 16 + l15];

#pragma unroll
  for (int mt = 0; mt < 4; ++mt)
#pragma unroll
    for (int r = 0; r < 4; ++r) {
      long grow = (long)moff + m0 + wrow + mt * 16 + quad * 4 + r;
      float rs = 0.f;
#pragma unroll
      for (int nt = 0; nt < 4; ++nt) {
        int col = n0 + wcol + nt * 16 + l15;
        float sv = tanhf(acc[mt][nt][r] + bvs[nt]);
        rs += sv;
        long idx = grow * (2 * D1) + off + col;
        float y = x[idx] * __expf(sv) + y_out[idx];   // y_out holds t
        y_out[idx] = y;
        if (y_bf) y_bf[grow * D1 + col] = f2bf(y);
      }
#pragma unroll
      for (int o = 8; o > 0; o >>= 1) rs += __shfl_down(rs, o, 16);
      if (l15 == 0) atomicAdd(&rowsum[wrow + mt * 16 + quad * 4 + r], rs);
    }
  __syncthreads();
  if (tid < BM) atomicAdd(&ld_out[moff + m0 + tid], rowsum[tid]);
}

// ---------------------------------------------------------------------------
// All 8 weight transposes in one dispatch. z in [0,8): z<4 -> W1 (1024x4096
// -> 4096x1024), z>=4 -> W2 (4096x1024 -> 1024x4096).
// grid: (128, 32, 8), block 256.
// ---------------------------------------------------------------------------
__global__ __launch_bounds__(256)
void transpose_all(const float* __restrict__ i0, const float* __restrict__ i1,
                   const float* __restrict__ i2, const float* __restrict__ i3,
                   const float* __restrict__ i4, const float* __restrict__ i5,
                   const float* __restrict__ i6, const float* __restrict__ i7,
                   unsigned short* __restrict__ o0, unsigned short* __restrict__ o1,
                   unsigned short* __restrict__ o2, unsigned short* __restrict__ o3,
                   unsigned short* __restrict__ o4, unsigned short* __restrict__ o5,
                   unsigned short* __restrict__ o6, unsigned short* __restrict__ o7) {
  const float* ins[8]  = {i0, i1, i2, i3, i4, i5, i6, i7};
  unsigned short* outs[8] = {o0, o1, o2, o3, o4, o5, o6, o7};
  const int z = blockIdx.z;
  const float* in = ins[z];
  unsigned short* out = outs[z];
  const int R = (z < 4) ? D1 : HDIM;    // input rows
  const int C = (z < 4) ? HDIM : D1;    // input cols
  const int bx = ((z < 4) ? blockIdx.x : blockIdx.y) * 32;  // over C
  const int by = ((z < 4) ? blockIdx.y : blockIdx.x) * 32;  // over R

  __shared__ float tile[32][33];
  const int tx = threadIdx.x & 31;
  const int ty = threadIdx.x >> 5;
  for (int j = ty; j < 32; j += 8)
    tile[j][tx] = in[(long)(by + j) * C + bx + tx];
  __syncthreads();
  for (int j = ty; j < 32; j += 8)
    out[(long)(bx + j) * R + by + tx] = f2bf(tile[tx][j]);
}

// x (B, 2048) fp32 -> x2 bf16 packed (B, 1024); also zeroes ld_out.
__global__ __launch_bounds__(256)
void cast_x2(const float* __restrict__ x, unsigned short* __restrict__ x2b,
             float* __restrict__ ld_out) {
  long i = (long)blockIdx.x * 256 + threadIdx.x;
  long row = i >> 10, col = i & 1023;
  x2b[i] = f2bf(x[row * (2 * D1) + D1 + col]);
  if (i < BDIM) ld_out[i] = 0.f;
}

// ---------------------------------------------------------------------------
extern "C" void kernel_launch(void* const* d_in, const int* in_sizes, int n_in,
                              void* d_out, int out_size, void* d_ws, size_t ws_size,
                              hipStream_t stream) {
  const float* x     = (const float*)d_in[0];
  const float* s1_W1 = (const float*)d_in[1];
  const float* s1_b1 = (const float*)d_in[2];
  const float* s1_W2 = (const float*)d_in[3];
  const float* s1_b2 = (const float*)d_in[4];
  const float* t1_W1 = (const float*)d_in[5];
  const float* t1_b1 = (const float*)d_in[6];
  const float* t1_W2 = (const float*)d_in[7];
  const float* t1_b2 = (const float*)d_in[8];
  const float* s2_W1 = (const float*)d_in[9];
  const float* s2_b1 = (const float*)d_in[10];
  const float* s2_W2 = (const float*)d_in[11];
  const float* s2_b2 = (const float*)d_in[12];
  const float* t2_W1 = (const float*)d_in[13];
  const float* t2_b1 = (const float*)d_in[14];
  const float* t2_W2 = (const float*)d_in[15];
  const float* t2_b2 = (const float*)d_in[16];

  const size_t MB = 1024UL * 1024UL;
  // ws: w1t 4x8MB @0 | w2t 4x8MB @32MB | xyb 16MB @64MB | h_s,h_t @80MB
  int NC = 32;
  {
    const int cand[6] = {1, 2, 4, 8, 16, 32};
    for (int i = 0; i < 6; ++i) {
      size_t need = 80 * MB + (128 * MB) / (size_t)cand[i];
      if (need <= ws_size) { NC = cand[i]; break; }
    }
  }
  const int Mrows = BDIM / NC;

  char* ws = (char*)d_ws;
  unsigned short* w1t[4], * w2t[4];
  for (int i = 0; i < 4; ++i) {
    w1t[i] = (unsigned short*)(ws + (8 * (size_t)i) * MB);
    w2t[i] = (unsigned short*)(ws + (32 + 8 * (size_t)i) * MB);
  }
  unsigned short* xyb = (unsigned short*)(ws + 64 * MB);   // x2 bf16 -> y1 bf16
  size_t hbytes = (size_t)Mrows * HDIM * 2;
  unsigned short* h_s = (unsigned short*)(ws + 80 * MB);
  unsigned short* h_t = (unsigned short*)(ws + 80 * MB + hbytes);

  float* y_out  = (float*)d_out;                           // (B, 2048)
  float* ld_out = (float*)d_out + (long)BDIM * (2 * D1);   // (B,)

  // --- prep ---
  cast_x2<<<(BDIM * D1) / 256, 256, 0, stream>>>(x, xyb, ld_out);
  transpose_all<<<dim3(HDIM / 32, D1 / 32, 8), 256, 0, stream>>>(
      s1_W1, t1_W1, s2_W1, t2_W1, s1_W2, t1_W2, s2_W2, t2_W2,
      w1t[0], w1t[1], w1t[2], w1t[3], w2t[0], w2t[1], w2t[2], w2t[3]);

  // --- per-chunk pipeline ---
  for (int c = 0; c < NC; ++c) {
    const int moff = c * Mrows;
    unsigned short* xA = xyb + (size_t)moff * D1;  // x2 (stage0) / y1 (stage1) bf16

    // ---- stage 0 (s1/t1 on x2 -> y1 in cols [0,1024)) ----
    gemm_bt<<<dim3(HDIM / BN, Mrows / BM, 2), 256, 0, stream>>>(
        xA, xA, w1t[0], w1t[1], s1_b1, t1_b1, h_s, h_t,
        Mrows, HDIM, D1, 0, HDIM, 0, 0);
    // t-path: t -> y_out[:, 0:1024) (fp32)
    gemm_bt<<<dim3(D1 / BN, Mrows / BM, 1), 256, 0, stream>>>(
        h_t, h_t, w2t[1], w2t[1], t1_b2, t1_b2, y_out, y_out,
        Mrows, D1, HDIM, 1, 2 * D1, 0, moff);
    // s-path + coupling: y1 = x1*exp(tanh(s)) + t, y1 bf16 -> xyb
    gemm2_s<<<dim3(D1 / BN, Mrows / BM), 256, 0, stream>>>(
        h_s, w2t[0], s1_b2, x, y_out, xA, ld_out, moff, 0);

    // ---- stage 1 (s2/t2 on y1 -> y2 in cols [1024,2048)) ----
    gemm_bt<<<dim3(HDIM / BN, Mrows / BM, 2), 256, 0, stream>>>(
        xA, xA, w1t[2], w1t[3], s2_b1, t2_b1, h_s, h_t,
        Mrows, HDIM, D1, 0, HDIM, 0, 0);
    gemm_bt<<<dim3(D1 / BN, Mrows / BM, 1), 256, 0, stream>>>(
        h_t, h_t, w2t[3], w2t[3], t2_b2, t2_b2, y_out, y_out,
        Mrows, D1, HDIM, 1, 2 * D1, D1, moff);
    gemm2_s<<<dim3(D1 / BN, Mrows / BM), 256, 0, stream>>>(
        h_s, w2t[2], s2_b2, x, y_out, nullptr, ld_out, moff, D1);
  }
}